// Round 5
// baseline (215.985 us; speedup 1.0000x reference)
//
#include <hip/hip_runtime.h>

typedef unsigned short u16;
typedef __attribute__((ext_vector_type(8))) short bf16x8;
typedef __attribute__((ext_vector_type(16))) float f32x16;

#define BK 64

__device__ __forceinline__ u16 f2bf(float f) {
    unsigned u = __float_as_uint(f);
    unsigned r = u + 0x7fffu + ((u >> 16) & 1u);
    return (u16)(r >> 16);
}
__device__ __forceinline__ float bf2f(u16 h) {
    return __uint_as_float(((unsigned)h) << 16);
}

__device__ __forceinline__ void gload_lds16(const u16* g, u16* l) {
    __builtin_amdgcn_global_load_lds(
        (__attribute__((address_space(1))) unsigned int*)(u16*)g,
        (__attribute__((address_space(3))) unsigned int*)l,
        16, 0, 0);
}

// ---------- fused input conversion + rowsum zeroing ----------
__global__ __launch_bounds__(256) void cvt_in_kernel(const float* __restrict__ x,
                                                     const float* __restrict__ W,
                                                     u16* __restrict__ xb,
                                                     u16* __restrict__ Wt,
                                                     float* __restrict__ rsum) {
    const int bid = blockIdx.x;
    const int tid = threadIdx.x;
    if (bid < 6144) {
        int i = bid * 256 + tid;
        float4 f = ((const float4*)x)[i];
        ushort4 u;
        u.x = f2bf(f.x); u.y = f2bf(f.y); u.z = f2bf(f.z); u.w = f2bf(f.w);
        ((ushort4*)xb)[i] = u;
    } else if (bid < 7872) {
        __shared__ float t[32][33];
        const int b = bid - 6144;
        const int j = b / 576;
        const int rem = b - j * 576;
        const int d0 = (rem % 24) * 32, o0 = (rem / 24) * 32;
        const int tx = tid & 31, ty = tid >> 5;
#pragma unroll
        for (int i = 0; i < 4; i++) {
            int d = d0 + ty + i * 8;
            t[ty + i * 8][tx] = W[((long)j * 768 + d) * 768 + o0 + tx];
        }
        __syncthreads();
#pragma unroll
        for (int i = 0; i < 4; i++) {
            int o = o0 + ty + i * 8;
            Wt[((long)j * 768 + o) * 768 + d0 + tx] = f2bf(t[tx][ty + i * 8]);
        }
    } else {
        const float4 z4 = {0.f, 0.f, 0.f, 0.f};
#pragma unroll
        for (int j = 0; j < 8; j++) ((float4*)rsum)[tid * 8 + j] = z4;
    }
}

// ---------- GEMM on mfma_f32_32x32x16_bf16: C = A(MxK) * Bt(NxK)^T ----------
// 4 waves; wave tile = (TMW*32) x 64; block = (TMW*64) x 128.
// A-frag: m=lane&31, k=(lane>>5)*8+j.  C/D: col=lane&31, row=(reg&3)+8*(reg>>2)+4*(lane>>5).
// MODE 0: QKV. y<12 -> Q/K bf16 direct; y>=12 -> V written TRANSPOSED (Vt) via LDS.
// MODE 1: P~ = exp(s*scale) bf16 + per-row atomic sum into rsum.
// MODE 2: out = acc / rsum[row] -> fp32.
template <int MODE, int TMW>
__global__ __launch_bounds__(256)
void gemm_bt_kernel(const u16* __restrict__ A, const u16* __restrict__ Bt,
                    u16* __restrict__ o16, float* __restrict__ o32,
                    u16* __restrict__ vt, float* __restrict__ rsum,
                    int K, long sA, long sB, long sO, int ldc, float scale) {
    constexpr int BM = TMW * 64;
    constexpr int SMEM_U16 = (MODE == 0) ? (128 * 136) : ((BM + 128) * BK);
    __shared__ u16 smem[SMEM_U16];
    u16* As = smem;
    u16* Bs = smem + BM * BK;

    const int tid = threadIdx.x;
    const int lane = tid & 63;
    const int wave = tid >> 6;
    const int z = blockIdx.z;

    const u16* Ab = A + (long)z * sA + (long)blockIdx.x * BM * K;
    const u16* Bb = Bt + (long)z * sB + (long)blockIdx.y * 128 * K;

    const int rl = lane >> 3;   // row within 8-row staging group
    const int pc = lane & 7;    // 16B chunk position within row
    const int c = lane & 31;    // MFMA col / m-row lane index
    const int h = lane >> 5;    // lane half
    const int wm = (wave >> 1) * (TMW * 32);
    const int wn = (wave & 1) * 64;

    f32x16 acc[TMW][2];
#pragma unroll
    for (int i = 0; i < TMW; i++)
#pragma unroll
        for (int j = 0; j < 2; j++)
#pragma unroll
            for (int e = 0; e < 16; e++) acc[i][j][e] = 0.f;

    for (int k0 = 0; k0 < K; k0 += BK) {
        // XOR swizzle: LDS row r position p holds global chunk p^(r&7)
#pragma unroll
        for (int t = 0; t < TMW * 2; ++t) {
            const int issue = wave + t * 4;      // wave-uniform
            const int row = issue * 8 + rl;
            const int gc = pc ^ (row & 7);
            gload_lds16(Ab + (long)row * K + k0 + gc * 8, &As[issue * 512]);
        }
#pragma unroll
        for (int t = 0; t < 4; ++t) {
            const int issue = wave + t * 4;
            const int row = issue * 8 + rl;
            const int gc = pc ^ (row & 7);
            gload_lds16(Bb + (long)row * K + k0 + gc * 8, &Bs[issue * 512]);
        }
        __syncthreads();
#pragma unroll
        for (int kk = 0; kk < BK; kk += 16) {
            const int cc = (kk >> 3) + h;        // desired global chunk
            bf16x8 af[TMW], bfr[2];
#pragma unroll
            for (int mi = 0; mi < TMW; ++mi) {
                const int R = wm + mi * 32 + c;
                af[mi] = *(const bf16x8*)&As[R * 64 + ((cc ^ (R & 7)) << 3)];
            }
#pragma unroll
            for (int ni = 0; ni < 2; ++ni) {
                const int R = wn + ni * 32 + c;
                bfr[ni] = *(const bf16x8*)&Bs[R * 64 + ((cc ^ (R & 7)) << 3)];
            }
#pragma unroll
            for (int mi = 0; mi < TMW; ++mi)
#pragma unroll
                for (int ni = 0; ni < 2; ++ni)
                    acc[mi][ni] = __builtin_amdgcn_mfma_f32_32x32x16_bf16(
                        af[mi], bfr[ni], acc[mi][ni], 0, 0, 0);
        }
        __syncthreads();
    }

    const int rowb = blockIdx.x * BM + wm;

    if (MODE == 0 && blockIdx.y >= 12) {
        // V segment -> Vt[b][o][s] via LDS transpose tile T[128 o][136 pad s]
        u16* T = smem;
#pragma unroll
        for (int mi = 0; mi < TMW; ++mi)
#pragma unroll
            for (int ni = 0; ni < 2; ++ni) {
                const int ol = wn + ni * 32 + c;
#pragma unroll
                for (int r = 0; r < 16; ++r) {
                    const int sl = wm + mi * 32 + (r & 3) + 8 * (r >> 2) + 4 * h;
                    T[ol * 136 + sl] = f2bf(acc[mi][ni][r]);
                }
            }
        __syncthreads();
        const int b = blockIdx.x >> 4;
        const int s0 = (blockIdx.x & 15) * 128;
        const int o0 = (blockIdx.y - 12) * 128;
        const int ol = tid >> 1, sh = (tid & 1) * 64;
        u16* dst = vt + ((long)b * 768 + o0 + ol) * 2048 + s0 + sh;
        const u16* src = &T[ol * 136 + sh];
#pragma unroll
        for (int j = 0; j < 8; ++j)
            *(uint4*)(dst + j * 8) = *(const uint4*)(src + j * 8);
        return;
    }

#pragma unroll
    for (int mi = 0; mi < TMW; ++mi) {
        if (MODE == 0) {
            const int seg = blockIdx.y / 6;           // 0=Q, 1=K (block-uniform)
#pragma unroll
            for (int ni = 0; ni < 2; ++ni) {
                const int ocol = blockIdx.y * 128 + wn + ni * 32 + c - seg * 768;
#pragma unroll
                for (int r = 0; r < 16; ++r) {
                    const int row = rowb + mi * 32 + (r & 3) + 8 * (r >> 2) + 4 * h;
                    o16[(long)seg * 6291456 + (long)row * 768 + ocol] =
                        f2bf(acc[mi][ni][r]);
                }
            }
        } else if (MODE == 1) {
            u16* dst = o16 + (long)z * sO;
            float rs[16];
#pragma unroll
            for (int r = 0; r < 16; ++r) rs[r] = 0.f;
#pragma unroll
            for (int ni = 0; ni < 2; ++ni) {
                const int col = blockIdx.y * 128 + wn + ni * 32 + c;
#pragma unroll
                for (int r = 0; r < 16; ++r) {
                    const int row = rowb + mi * 32 + (r & 3) + 8 * (r >> 2) + 4 * h;
                    const float p = __expf(acc[mi][ni][r] * scale);
                    const u16 pb = f2bf(p);
                    dst[(long)row * ldc + col] = pb;
                    rs[r] += bf2f(pb);
                }
            }
#pragma unroll
            for (int r = 0; r < 16; ++r) {
#pragma unroll
                for (int off = 1; off <= 16; off <<= 1) rs[r] += __shfl_xor(rs[r], off);
                if (c == 0)
                    atomicAdd(&rsum[z * 2048 + rowb + mi * 32 +
                                    (r & 3) + 8 * (r >> 2) + 4 * h], rs[r]);
            }
        } else {
            float* dst = o32 + (long)z * sO;
            float inv[16];
#pragma unroll
            for (int g = 0; g < 4; ++g) {
                const float4 rs4 = *(const float4*)&rsum[z * 2048 + rowb + mi * 32 +
                                                         g * 8 + 4 * h];
                inv[g * 4 + 0] = 1.f / rs4.x;
                inv[g * 4 + 1] = 1.f / rs4.y;
                inv[g * 4 + 2] = 1.f / rs4.z;
                inv[g * 4 + 3] = 1.f / rs4.w;
            }
#pragma unroll
            for (int ni = 0; ni < 2; ++ni) {
                const int col = blockIdx.y * 128 + wn + ni * 32 + c;
#pragma unroll
                for (int r = 0; r < 16; ++r) {
                    const int row = rowb + mi * 32 + (r & 3) + 8 * (r >> 2) + 4 * h;
                    dst[(long)row * ldc + col] = acc[mi][ni][r] * inv[r];
                }
            }
        }
    }
}

extern "C" void kernel_launch(void* const* d_in, const int* in_sizes, int n_in,
                              void* d_out, int out_size, void* d_ws, size_t ws_size,
                              hipStream_t stream) {
    const float* x = (const float*)d_in[0];     // [4,2048,768]
    const float* w = (const float*)d_in[1];     // [3,768,768]
    float* out = (float*)d_out;                 // [4,2048,768]

    const long NX = 6291456L;   // 4*2048*768
    const long NS = 16777216L;  // 4*2048*2048

    // layout: [Sb: NS][Qb: NX][Kb: NX][Vt: NX][rowsum: 8192 f32]  (~71.3 MB)
    // xb+wt overlay the Sb region (dead before GEMM2 writes Sb)
    u16* Sb = (u16*)d_ws;
    u16* xb = Sb;                 // NX
    u16* wt = Sb + NX;            // 1769472  (< NS)
    u16* Qb = Sb + NS;
    u16* Kb = Qb + NX;
    u16* Vt = Kb + NX;
    float* rowsum = (float*)(Vt + NX);

    // 1. x -> bf16; W -> Wt[2304][768] bf16 transposed; rowsum <- 0
    cvt_in_kernel<<<7873, 256, 0, stream>>>(x, w, xb, wt, rowsum);
    // 2. QKV: [8192,768] x [2304,768]^T; Q,K direct; V transposed into Vt
    //    128x128 blocks -> 64x18 = 1152 blocks
    gemm_bt_kernel<0, 2><<<dim3(64, 18, 1), 256, 0, stream>>>(
        xb, wt, Qb, nullptr, Vt, nullptr, 768, 0L, 0L, 0L, 768, 1.0f);
    // 3. P~ = exp(QK^T/sqrt(300)) bf16 -> Sb, + rowsum atomics
    //    128x128 blocks -> 16x16x4 = 1024 blocks = 4.0/CU
    gemm_bt_kernel<1, 2><<<dim3(16, 16, 4), 256, 0, stream>>>(
        Qb, Kb, Sb, nullptr, nullptr, rowsum, 768, 2048L * 768, 2048L * 768,
        2048L * 2048, 2048, 0.057735026918962574f);
    // 4. out = (P~ x Vt^T) / rowsum -> fp32
    //    64x128 blocks -> 32x6x4 = 768 blocks = 3.0/CU
    gemm_bt_kernel<2, 1><<<dim3(32, 6, 4), 256, 0, stream>>>(
        Sb, Vt, nullptr, out, nullptr, rowsum, 2048, 2048L * 2048, 768L * 2048,
        2048L * 768, 768, 1.0f);
}

// Round 6
// 204.936 us; speedup vs baseline: 1.0539x; 1.0539x over previous
//
#include <hip/hip_runtime.h>

typedef unsigned short u16;
typedef __attribute__((ext_vector_type(8))) short bf16x8;
typedef __attribute__((ext_vector_type(4))) float f32x4;

#define BK 128

__device__ __forceinline__ u16 f2bf(float f) {
    unsigned u = __float_as_uint(f);
    unsigned r = u + 0x7fffu + ((u >> 16) & 1u);
    return (u16)(r >> 16);
}
__device__ __forceinline__ float bf2f(u16 h) {
    return __uint_as_float(((unsigned)h) << 16);
}

__device__ __forceinline__ void gload_lds16(const u16* g, u16* l) {
    __builtin_amdgcn_global_load_lds(
        (__attribute__((address_space(1))) unsigned int*)(u16*)g,
        (__attribute__((address_space(3))) unsigned int*)l,
        16, 0, 0);
}

// ---------- fused input conversion + rowsum zeroing ----------
// blocks [0,6144): x fp32 -> bf16 (float4/thread)
// blocks [6144,7872): kernel[3][768][768] fp32 -> Wt[j*768+o][d] bf16 (transpose)
// block 7872: zero rowsum[8192]
__global__ __launch_bounds__(256) void cvt_in_kernel(const float* __restrict__ x,
                                                     const float* __restrict__ W,
                                                     u16* __restrict__ xb,
                                                     u16* __restrict__ Wt,
                                                     float* __restrict__ rsum) {
    const int bid = blockIdx.x;
    const int tid = threadIdx.x;
    if (bid < 6144) {
        int i = bid * 256 + tid;
        float4 f = ((const float4*)x)[i];
        ushort4 u;
        u.x = f2bf(f.x); u.y = f2bf(f.y); u.z = f2bf(f.z); u.w = f2bf(f.w);
        ((ushort4*)xb)[i] = u;
    } else if (bid < 7872) {
        __shared__ float t[32][33];
        const int b = bid - 6144;
        const int j = b / 576;
        const int rem = b - j * 576;
        const int d0 = (rem % 24) * 32, o0 = (rem / 24) * 32;
        const int tx = tid & 31, ty = tid >> 5;
#pragma unroll
        for (int i = 0; i < 4; i++) {
            int d = d0 + ty + i * 8;
            t[ty + i * 8][tx] = W[((long)j * 768 + d) * 768 + o0 + tx];
        }
        __syncthreads();
#pragma unroll
        for (int i = 0; i < 4; i++) {
            int o = o0 + ty + i * 8;
            Wt[((long)j * 768 + o) * 768 + d0 + tx] = f2bf(t[tx][ty + i * 8]);
        }
    } else {
        const float4 z4 = {0.f, 0.f, 0.f, 0.f};
#pragma unroll
        for (int j = 0; j < 8; j++) ((float4*)rsum)[tid * 8 + j] = z4;
    }
}

// ---------- GEMM: C = A(MxK) * Bt(NxK)^T, bf16 in, fp32 acc, 16x16x32 core ----------
// TM=2 (BM=64); BN=128. BK=128: row = 16 chunks of 16B; XOR swizzle over 16 chunks.
// Staging issue = 1024B = 4 rows; lane -> (rl=lane>>4 row, pc=lane&15 chunk pos).
// MODE 0: QKV. y<12 -> Q/K bf16 direct; y>=12 -> V written TRANSPOSED (Vt) via LDS.
// MODE 1: P~ = exp(s*scale) bf16 + per-row atomic sum into rsum.
// MODE 2: out = acc / rsum[row] -> fp32.
template <int MODE, int TM>
__global__ __launch_bounds__(256)
void gemm_bt_kernel(const u16* __restrict__ A, const u16* __restrict__ Bt,
                    u16* __restrict__ o16, float* __restrict__ o32,
                    u16* __restrict__ vt, float* __restrict__ rsum,
                    int K, long sA, long sB, long sO, int ldc, float scale) {
    constexpr int BM = TM * 32;
    __shared__ u16 smem[(BM + 128) * BK];   // staging; reused for V transpose
    u16* As = smem;
    u16* Bs = smem + BM * BK;

    const int tid = threadIdx.x;
    const int lane = tid & 63;
    const int wave = tid >> 6;
    const int z = blockIdx.z;

    const u16* Ab = A + (long)z * sA + (long)blockIdx.x * BM * K;
    const u16* Bb = Bt + (long)z * sB + (long)blockIdx.y * 128 * K;

    const int rl = lane >> 4;   // row within 4-row staging group
    const int pc = lane & 15;   // 16B chunk position within row
    const int q = lane >> 4;    // quad
    const int rA = lane & 15;
    const int wm = (wave >> 1) * (TM * 16);
    const int wn = (wave & 1) * 64;

    f32x4 acc[TM][4];
    const f32x4 zero = {0.f, 0.f, 0.f, 0.f};
#pragma unroll
    for (int i = 0; i < TM; i++)
#pragma unroll
        for (int j = 0; j < 4; j++) acc[i][j] = zero;

    for (int k0 = 0; k0 < K; k0 += BK) {
        // XOR swizzle: LDS row r position p holds global chunk p^(r&15)
#pragma unroll
        for (int t = 0; t < TM * 2; ++t) {           // A: BM*128/512 = TM*8 issues
            const int issue = wave + t * 4;          // wave-uniform
            const int row = issue * 4 + rl;
            const int gc = pc ^ (row & 15);
            gload_lds16(Ab + (long)row * K + k0 + gc * 8, &As[issue * 512]);
        }
#pragma unroll
        for (int t = 0; t < 8; ++t) {                // B: 128*128/512 = 32 issues
            const int issue = wave + t * 4;
            const int row = issue * 4 + rl;
            const int gc = pc ^ (row & 15);
            gload_lds16(Bb + (long)row * K + k0 + gc * 8, &Bs[issue * 512]);
        }
        __syncthreads();
#pragma unroll
        for (int kk = 0; kk < BK; kk += 32) {
            const int gchunk = (kk >> 3) + q;        // desired global chunk index
            bf16x8 af[TM], bfr[4];
#pragma unroll
            for (int mi = 0; mi < TM; ++mi) {
                const int R = wm + mi * 16 + rA;
                af[mi] = *(const bf16x8*)&As[R * BK + ((gchunk ^ (R & 15)) << 3)];
            }
#pragma unroll
            for (int ni = 0; ni < 4; ++ni) {
                const int R = wn + ni * 16 + rA;
                bfr[ni] = *(const bf16x8*)&Bs[R * BK + ((gchunk ^ (R & 15)) << 3)];
            }
#pragma unroll
            for (int mi = 0; mi < TM; ++mi)
#pragma unroll
                for (int ni = 0; ni < 4; ++ni)
                    acc[mi][ni] = __builtin_amdgcn_mfma_f32_16x16x32_bf16(
                        af[mi], bfr[ni], acc[mi][ni], 0, 0, 0);
        }
        __syncthreads();
    }

    // epilogue: C/D layout col=lane&15, row=quad*4+reg
    const int rowb = blockIdx.x * BM + wm + q * 4;
    const int colb = blockIdx.y * 128 + wn + rA;

    if (MODE == 0 && blockIdx.y >= 12) {
        // V segment -> write transposed (Vt[b][o][s]) via LDS tile [128 o][72 pad]
        u16* T = smem;
#pragma unroll
        for (int mi = 0; mi < TM; ++mi)
#pragma unroll
            for (int ni = 0; ni < 4; ++ni) {
                const int lc = wn + ni * 16 + rA;
#pragma unroll
                for (int r = 0; r < 4; ++r) {
                    const int lr = wm + mi * 16 + q * 4 + r;
                    T[lc * 72 + lr] = f2bf(acc[mi][ni][r]);
                }
            }
        __syncthreads();
        const int b = blockIdx.x >> 5;
        const int s0 = (blockIdx.x & 31) * 64;
        const int o0 = (blockIdx.y - 12) * 128;
        const int ol = tid >> 1, h = (tid & 1) * 32;
        u16* dst = vt + ((long)b * 768 + o0 + ol) * 2048 + s0 + h;
        const u16* src = &T[ol * 72 + h];
#pragma unroll
        for (int j = 0; j < 4; ++j)
            *(uint4*)(dst + j * 8) = *(const uint4*)(src + j * 8);
        return;
    }

#pragma unroll
    for (int mi = 0; mi < TM; ++mi) {
        if (MODE == 0) {
            const int seg = blockIdx.y / 6;           // 0=Q, 1=K (block-uniform)
            const int ocol = colb - seg * 768;
#pragma unroll
            for (int ni = 0; ni < 4; ++ni)
#pragma unroll
                for (int r = 0; r < 4; ++r)
                    o16[(long)seg * 6291456 + (long)(rowb + mi * 16 + r) * 768 +
                        ocol + ni * 16] = f2bf(acc[mi][ni][r]);
        } else if (MODE == 1) {
            u16* dst = o16 + (long)z * sO;
            float rs[4] = {0.f, 0.f, 0.f, 0.f};
#pragma unroll
            for (int ni = 0; ni < 4; ++ni)
#pragma unroll
                for (int r = 0; r < 4; ++r) {
                    const float p = __expf(acc[mi][ni][r] * scale);
                    const u16 pb = f2bf(p);
                    dst[(long)(rowb + mi * 16 + r) * ldc + colb + ni * 16] = pb;
                    rs[r] += bf2f(pb);
                }
#pragma unroll
            for (int r = 0; r < 4; ++r) {
#pragma unroll
                for (int off = 1; off <= 8; off <<= 1) rs[r] += __shfl_xor(rs[r], off);
                if (rA == 0)
                    atomicAdd(&rsum[z * 2048 + rowb + mi * 16 + r], rs[r]);
            }
        } else {
            float* dst = o32 + (long)z * sO;
            const float4 rs4 = *(const float4*)&rsum[z * 2048 + rowb + mi * 16];
            const float inv[4] = {1.f / rs4.x, 1.f / rs4.y, 1.f / rs4.z, 1.f / rs4.w};
#pragma unroll
            for (int ni = 0; ni < 4; ++ni)
#pragma unroll
                for (int r = 0; r < 4; ++r)
                    dst[(long)(rowb + mi * 16 + r) * ldc + colb + ni * 16] =
                        acc[mi][ni][r] * inv[r];
        }
    }
}

extern "C" void kernel_launch(void* const* d_in, const int* in_sizes, int n_in,
                              void* d_out, int out_size, void* d_ws, size_t ws_size,
                              hipStream_t stream) {
    const float* x = (const float*)d_in[0];     // [4,2048,768]
    const float* w = (const float*)d_in[1];     // [3,768,768]
    float* out = (float*)d_out;                 // [4,2048,768]

    const long NX = 6291456L;   // 4*2048*768
    const long NS = 16777216L;  // 4*2048*2048

    // layout: [Sb: NS][Qb: NX][Kb: NX][Vt: NX][rowsum: 8192 f32]  (~71.3 MB)
    // xb+wt overlay the Sb region (dead before GEMM2 writes Sb)
    u16* Sb = (u16*)d_ws;
    u16* xb = Sb;                 // NX
    u16* wt = Sb + NX;            // 1769472  (< NS)
    u16* Qb = Sb + NS;
    u16* Kb = Qb + NX;
    u16* Vt = Kb + NX;
    float* rowsum = (float*)(Vt + NX);

    // 1. x -> bf16; W -> Wt[2304][768] bf16 transposed; rowsum <- 0
    cvt_in_kernel<<<7873, 256, 0, stream>>>(x, w, xb, wt, rowsum);
    // 2. QKV: [8192,768] x [2304,768]^T; Q,K direct; V transposed into Vt
    //    BM=64 -> 128x18 = 2304 blocks; K=768 -> 6 BK-iters
    gemm_bt_kernel<0, 2><<<dim3(128, 18, 1), 256, 0, stream>>>(
        xb, wt, Qb, nullptr, Vt, nullptr, 768, 0L, 0L, 0L, 768, 1.0f);
    // 3. P~ = exp(QK^T/sqrt(300)) bf16 -> Sb, + rowsum atomics
    //    32x16x4 = 2048 blocks = 8.0/CU
    gemm_bt_kernel<1, 2><<<dim3(32, 16, 4), 256, 0, stream>>>(
        Qb, Kb, Sb, nullptr, nullptr, rowsum, 768, 2048L * 768, 2048L * 768,
        2048L * 2048, 2048, 0.057735026918962574f);
    // 4. out = (P~ x Vt^T) / rowsum -> fp32   (768 blocks = 3.0/CU; K=2048 -> 16 iters)
    gemm_bt_kernel<2, 2><<<dim3(32, 6, 4), 256, 0, stream>>>(
        Sb, Vt, nullptr, out, nullptr, rowsum, 2048, 2048L * 2048, 768L * 2048,
        2048L * 768, 768, 1.0f);
}

// Round 7
// 198.895 us; speedup vs baseline: 1.0859x; 1.0304x over previous
//
#include <hip/hip_runtime.h>

typedef unsigned short u16;
typedef __attribute__((ext_vector_type(8))) short bf16x8;
typedef __attribute__((ext_vector_type(4))) float f32x4;

__device__ __forceinline__ u16 f2bf(float f) {
    unsigned u = __float_as_uint(f);
    unsigned r = u + 0x7fffu + ((u >> 16) & 1u);
    return (u16)(r >> 16);
}
__device__ __forceinline__ float bf2f(u16 h) {
    return __uint_as_float(((unsigned)h) << 16);
}

__device__ __forceinline__ void gload_lds16(const u16* g, u16* l) {
    __builtin_amdgcn_global_load_lds(
        (__attribute__((address_space(1))) unsigned int*)(u16*)g,
        (__attribute__((address_space(3))) unsigned int*)l,
        16, 0, 0);
}

// ---------- fused input conversion + rowsum zeroing ----------
__global__ __launch_bounds__(256) void cvt_in_kernel(const float* __restrict__ x,
                                                     const float* __restrict__ W,
                                                     u16* __restrict__ xb,
                                                     u16* __restrict__ Wt,
                                                     float* __restrict__ rsum) {
    const int bid = blockIdx.x;
    const int tid = threadIdx.x;
    if (bid < 6144) {
        int i = bid * 256 + tid;
        float4 f = ((const float4*)x)[i];
        ushort4 u;
        u.x = f2bf(f.x); u.y = f2bf(f.y); u.z = f2bf(f.z); u.w = f2bf(f.w);
        ((ushort4*)xb)[i] = u;
    } else if (bid < 7872) {
        __shared__ float t[32][33];
        const int b = bid - 6144;
        const int j = b / 576;
        const int rem = b - j * 576;
        const int d0 = (rem % 24) * 32, o0 = (rem / 24) * 32;
        const int tx = tid & 31, ty = tid >> 5;
#pragma unroll
        for (int i = 0; i < 4; i++) {
            int d = d0 + ty + i * 8;
            t[ty + i * 8][tx] = W[((long)j * 768 + d) * 768 + o0 + tx];
        }
        __syncthreads();
#pragma unroll
        for (int i = 0; i < 4; i++) {
            int o = o0 + ty + i * 8;
            Wt[((long)j * 768 + o) * 768 + d0 + tx] = f2bf(t[tx][ty + i * 8]);
        }
    } else {
        const float4 z4 = {0.f, 0.f, 0.f, 0.f};
#pragma unroll
        for (int j = 0; j < 8; j++) ((float4*)rsum)[tid * 8 + j] = z4;
    }
}

// ---------- persistent pipelined GEMM: C = A(MxK) * Bt(NxK)^T ----------
// BM=64, BN=128, BK=64, 16x16x32 bf16 core, fp32 acc.
// Double-buffered LDS (2 x 24KB); ONE barrier per K-iter; stage(ki+1) (or next
// tile's k=0) issued right after the barrier so it overlaps compute(ki).
// Persistent blocks: tile_id = bid, bid+grid, ... (grids chosen so tile counts
// divide evenly: G1 768x3, G2 512x4, G3 768x1).
// MODE 0: QKV. y<12 -> Q/K bf16 direct; y>=12 -> V transposed into Vt via LDS.
// MODE 1: P~ = exp(s*scale) bf16 + per-row atomic rowsum.
// MODE 2: out = acc / rsum[row] -> fp32.
template <int MODE>
__global__ __launch_bounds__(256)
void gemm_bt_kernel(const u16* __restrict__ A, const u16* __restrict__ Bt,
                    u16* __restrict__ o16, float* __restrict__ o32,
                    u16* __restrict__ vt, float* __restrict__ rsum,
                    int K, long sA, long sB, long sO, int ldc, float scale,
                    int nX, int nY, int nTiles) {
    __shared__ u16 smem[2 * 12288];     // 2 x (64+128)x64 u16 = 48 KB

    const int tid = threadIdx.x;
    const int lane = tid & 63;
    const int wave = tid >> 6;

    const int rl = lane >> 3;   // staging: row within 8-row group
    const int pc = lane & 7;    // staging: 16B chunk position
    const int q = lane >> 4;    // quad
    const int rA = lane & 15;
    const int wm = (wave >> 1) * 32;
    const int wn = (wave & 1) * 64;

    const int KI = K >> 6;

    // stage one BK-slab of A (8 issues) and B (16 issues) into buffer `buf`
    auto stage = [&](int buf, const u16* Ap, const u16* Bp, int k0) {
        u16* As_ = smem + buf * 12288;
        u16* Bs_ = As_ + 4096;
#pragma unroll
        for (int t2 = 0; t2 < 2; ++t2) {
            const int issue = wave + t2 * 4;   // wave-uniform
            const int row = issue * 8 + rl;
            const int gc = pc ^ (row & 7);
            gload_lds16(Ap + (long)row * K + k0 + gc * 8, &As_[issue * 512]);
        }
#pragma unroll
        for (int t2 = 0; t2 < 4; ++t2) {
            const int issue = wave + t2 * 4;
            const int row = issue * 8 + rl;
            const int gc = pc ^ (row & 7);
            gload_lds16(Bp + (long)row * K + k0 + gc * 8, &Bs_[issue * 512]);
        }
    };

    int t = blockIdx.x;
    int x = t % nX;
    int r = t / nX;
    int y = r % nY;
    int z = r / nY;
    const u16* Ab = A + (long)z * sA + (long)x * 64 * K;
    const u16* Bb = Bt + (long)z * sB + (long)y * 128 * K;

    int cur = 0;
    stage(0, Ab, Bb, 0);                 // prologue

    for (; t < nTiles; t += gridDim.x) {
        const int xe = x, ye = y, ze = z;   // coords for this tile's epilogue

        f32x4 acc[2][4];
        const f32x4 zero = {0.f, 0.f, 0.f, 0.f};
#pragma unroll
        for (int i = 0; i < 2; i++)
#pragma unroll
            for (int j = 0; j < 4; j++) acc[i][j] = zero;

        for (int ki = 0; ki < KI; ++ki) {
            __syncthreads();             // drains stage for buf[cur] (issued 1 compute ago)
            const int nxt = cur ^ 1;
            if (ki + 1 < KI) {
                stage(nxt, Ab, Bb, (ki + 1) << 6);
            } else {
                const int t2 = t + gridDim.x;
                if (t2 < nTiles) {       // prefetch next tile's first slab
                    x = t2 % nX;
                    r = t2 / nX;
                    y = r % nY;
                    z = r / nY;
                    Ab = A + (long)z * sA + (long)x * 64 * K;
                    Bb = Bt + (long)z * sB + (long)y * 128 * K;
                    stage(nxt, Ab, Bb, 0);
                }
            }
            // compute on buf[cur]
            const u16* As_ = smem + cur * 12288;
            const u16* Bs_ = As_ + 4096;
#pragma unroll
            for (int kk = 0; kk < 64; kk += 32) {
                const int gchunk = (kk >> 3) + q;
                bf16x8 af[2], bfr[4];
#pragma unroll
                for (int mi = 0; mi < 2; ++mi) {
                    const int R = wm + mi * 16 + rA;
                    af[mi] = *(const bf16x8*)&As_[R * 64 + ((gchunk ^ (R & 7)) << 3)];
                }
#pragma unroll
                for (int ni = 0; ni < 4; ++ni) {
                    const int R = wn + ni * 16 + rA;
                    bfr[ni] = *(const bf16x8*)&Bs_[R * 64 + ((gchunk ^ (R & 7)) << 3)];
                }
#pragma unroll
                for (int mi = 0; mi < 2; ++mi)
#pragma unroll
                    for (int ni = 0; ni < 4; ++ni)
                        acc[mi][ni] = __builtin_amdgcn_mfma_f32_16x16x32_bf16(
                            af[mi], bfr[ni], acc[mi][ni], 0, 0, 0);
            }
            cur = nxt;
        }

        // ---- epilogue (overlaps the prefetched next-tile stage) ----
        // C/D layout: col=lane&15, row=quad*4+reg
        const int rowb = xe * 64 + wm + q * 4;
        const int colb = ye * 128 + wn + rA;

        if (MODE == 0 && ye >= 12) {
            // V segment -> Vt[b][o][s] via LDS tile [128 o][72 pad s] in the
            // buffer NOT targeted by the in-flight prefetch (= last-computed).
            u16* T = smem + (cur ^ 1) * 12288;
            __syncthreads();             // all waves done reading that buffer
#pragma unroll
            for (int mi = 0; mi < 2; ++mi)
#pragma unroll
                for (int ni = 0; ni < 4; ++ni) {
                    const int lc = wn + ni * 16 + rA;
#pragma unroll
                    for (int rr = 0; rr < 4; ++rr) {
                        const int lr = wm + mi * 16 + q * 4 + rr;
                        T[lc * 72 + lr] = f2bf(acc[mi][ni][rr]);
                    }
                }
            __syncthreads();
            const int b = xe >> 5;
            const int s0 = (xe & 31) * 64;
            const int o0 = (ye - 12) * 128;
            const int ol = tid >> 1, h = (tid & 1) * 32;
            u16* dst = vt + ((long)b * 768 + o0 + ol) * 2048 + s0 + h;
            const u16* src = &T[ol * 72 + h];
#pragma unroll
            for (int j = 0; j < 4; ++j)
                *(uint4*)(dst + j * 8) = *(const uint4*)(src + j * 8);
            continue;
        }

#pragma unroll
        for (int mi = 0; mi < 2; ++mi) {
            if (MODE == 0) {
                const int seg = ye / 6;           // 0=Q, 1=K (block-uniform)
                const int ocol = colb - seg * 768;
#pragma unroll
                for (int ni = 0; ni < 4; ++ni)
#pragma unroll
                    for (int rr = 0; rr < 4; ++rr)
                        o16[(long)seg * 6291456 + (long)(rowb + mi * 16 + rr) * 768 +
                            ocol + ni * 16] = f2bf(acc[mi][ni][rr]);
            } else if (MODE == 1) {
                u16* dst = o16 + (long)ze * sO;
                float rs[4] = {0.f, 0.f, 0.f, 0.f};
#pragma unroll
                for (int ni = 0; ni < 4; ++ni)
#pragma unroll
                    for (int rr = 0; rr < 4; ++rr) {
                        const float p = __expf(acc[mi][ni][rr] * scale);
                        const u16 pb = f2bf(p);
                        dst[(long)(rowb + mi * 16 + rr) * ldc + colb + ni * 16] = pb;
                        rs[rr] += bf2f(pb);
                    }
#pragma unroll
                for (int rr = 0; rr < 4; ++rr) {
#pragma unroll
                    for (int off = 1; off <= 8; off <<= 1)
                        rs[rr] += __shfl_xor(rs[rr], off);
                    if (rA == 0)
                        atomicAdd(&rsum[ze * 2048 + rowb + mi * 16 + rr], rs[rr]);
                }
            } else {
                float* dst = o32 + (long)ze * sO;
                const float4 rs4 = *(const float4*)&rsum[ze * 2048 + rowb + mi * 16];
                const float inv[4] = {1.f / rs4.x, 1.f / rs4.y, 1.f / rs4.z, 1.f / rs4.w};
#pragma unroll
                for (int ni = 0; ni < 4; ++ni)
#pragma unroll
                    for (int rr = 0; rr < 4; ++rr)
                        dst[(long)(rowb + mi * 16 + rr) * ldc + colb + ni * 16] =
                            acc[mi][ni][rr] * inv[rr];
            }
        }
    }
}

extern "C" void kernel_launch(void* const* d_in, const int* in_sizes, int n_in,
                              void* d_out, int out_size, void* d_ws, size_t ws_size,
                              hipStream_t stream) {
    const float* x = (const float*)d_in[0];     // [4,2048,768]
    const float* w = (const float*)d_in[1];     // [3,768,768]
    float* out = (float*)d_out;                 // [4,2048,768]

    const long NX = 6291456L;   // 4*2048*768
    const long NS = 16777216L;  // 4*2048*2048

    // layout: [Sb: NS][Qb: NX][Kb: NX][Vt: NX][rowsum: 8192 f32]
    // xb+wt overlay the Sb region (dead before GEMM2 writes Sb)
    u16* Sb = (u16*)d_ws;
    u16* xb = Sb;                 // NX
    u16* wt = Sb + NX;            // 1769472  (< NS)
    u16* Qb = Sb + NS;
    u16* Kb = Qb + NX;
    u16* Vt = Kb + NX;
    float* rowsum = (float*)(Vt + NX);

    // 1. x -> bf16; W -> Wt[2304][768] bf16 transposed; rowsum <- 0
    cvt_in_kernel<<<7873, 256, 0, stream>>>(x, w, xb, wt, rowsum);
    // 2. QKV: tiles 128x18 = 2304 = 768 blocks x 3  (3/CU co-resident)
    gemm_bt_kernel<0><<<768, 256, 0, stream>>>(
        xb, wt, Qb, nullptr, Vt, nullptr, 768, 0L, 0L, 0L, 768, 1.0f,
        128, 18, 2304);
    // 3. P~ = exp(QK^T/sqrt(300)): tiles 32x16x4 = 2048 = 512 blocks x 4
    gemm_bt_kernel<1><<<512, 256, 0, stream>>>(
        Qb, Kb, Sb, nullptr, nullptr, rowsum, 768, 2048L * 768, 2048L * 768,
        2048L * 2048, 2048, 0.057735026918962574f, 32, 16, 2048);
    // 4. out = (P~ x Vt^T)/rowsum: tiles 32x6x4 = 768 = 768 blocks x 1
    gemm_bt_kernel<2><<<768, 256, 0, stream>>>(
        Sb, Vt, nullptr, out, nullptr, rowsum, 2048, 2048L * 2048, 768L * 2048,
        2048L * 768, 768, 1.0f, 32, 6, 768);
}